// Round 11
// baseline (283.723 us; speedup 1.0000x reference)
//
#include <hip/hip_runtime.h>
#include <cstdint>

// NT-Xent loss via symmetric bf16-MFMA Gram + fused exp/row-sum epilogue.
//  S[r] = sum_{c!=r} exp((dot(n_r,n_c)-1)/tau); lse[r] = log(S[r]) + 1/tau.
//  R11: R6 base (best ksimlse: plain 2-buffer loop; R8/R9/R10 variants all
//  reverted) + LAST-BLOCK FINISHER: the final ksimlse block folds the loss
//  (non-blocking atomic-counter handshake, no spin). 3 -> 2 dispatches,
//  removing one ~30us inter-dispatch gap + kfinal.
// ws: [0,8MiB) E bf16 8192x512 | S[8192] f32 | pd[4096] f32 | cnt u32

#define B_ROWS 4096
#define NROWS  8192
#define DIM    512
#define NTILES 2080   // 64 diag + 2016 strict-upper 128x128 tiles

typedef unsigned short u16;

constexpr float INV_TAU    = 1.0f / 0.07f;
constexpr float POS_THRESH = 0.2f;
constexpr int BM = 128, BN = 128, BK = 32;
constexpr int KSTEPS = DIM / BK;   // 16

using f32x4  = __attribute__((ext_vector_type(4))) float;
using bf16x8 = __attribute__((ext_vector_type(8))) short;

static __device__ __forceinline__ u16 f2bf(float f) {
  union { float f; uint32_t u; } v; v.f = f;
  uint32_t r = v.u + 0x7fffu + ((v.u >> 16) & 1u);  // RNE
  return (u16)(r >> 16);
}

static __device__ __forceinline__ void gload16(const u16* g, void* l) {
  __builtin_amdgcn_global_load_lds(
      (const __attribute__((address_space(1))) void*)g,
      (__attribute__((address_space(3))) void*)l, 16, 0, 0);
}

static __device__ __forceinline__ float aload(const float* p) {
  return __hip_atomic_load(p, __ATOMIC_RELAXED, __HIP_MEMORY_SCOPE_AGENT);
}

// ---- knorm2: one wave per pair k. Normalize rows k and k+B to bf16,
//      fp32 pair cosine, zero S + tile counter. ----
__global__ __launch_bounds__(256) void knorm2(const float* __restrict__ ei,
                                              const float* __restrict__ ej,
                                              u16* __restrict__ E,
                                              float* __restrict__ S,
                                              float* __restrict__ pd,
                                              unsigned int* __restrict__ cnt) {
  if (blockIdx.x == 0 && threadIdx.x == 0) *cnt = 0u;
  const int k    = (blockIdx.x * 256 + threadIdx.x) >> 6;  // pair 0..4095
  const int lane = threadIdx.x & 63;
  const float4* pi = (const float4*)(ei + (size_t)k * DIM);
  const float4* pj = (const float4*)(ej + (size_t)k * DIM);
  float4 a[2] = { pi[lane * 2], pi[lane * 2 + 1] };
  float4 b[2] = { pj[lane * 2], pj[lane * 2 + 1] };
  float si = 0.f, sj = 0.f, dot = 0.f;
#pragma unroll
  for (int h = 0; h < 2; ++h) {
    si  += a[h].x*a[h].x + a[h].y*a[h].y + a[h].z*a[h].z + a[h].w*a[h].w;
    sj  += b[h].x*b[h].x + b[h].y*b[h].y + b[h].z*b[h].z + b[h].w*b[h].w;
    dot += a[h].x*b[h].x + a[h].y*b[h].y + a[h].z*b[h].z + a[h].w*b[h].w;
  }
#pragma unroll
  for (int m = 1; m < 64; m <<= 1) {
    si += __shfl_xor(si, m); sj += __shfl_xor(sj, m); dot += __shfl_xor(dot, m);
  }
  const float invi = 1.0f / sqrtf(si);
  const float invj = 1.0f / sqrtf(sj);
  union { u16 us[8]; uint4 v; } pk;
#pragma unroll
  for (int h = 0; h < 2; ++h) {
    pk.us[h*4+0] = f2bf(a[h].x * invi); pk.us[h*4+1] = f2bf(a[h].y * invi);
    pk.us[h*4+2] = f2bf(a[h].z * invi); pk.us[h*4+3] = f2bf(a[h].w * invi);
  }
  ((uint4*)(E + (size_t)k * DIM))[lane] = pk.v;
#pragma unroll
  for (int h = 0; h < 2; ++h) {
    pk.us[h*4+0] = f2bf(b[h].x * invj); pk.us[h*4+1] = f2bf(b[h].y * invj);
    pk.us[h*4+2] = f2bf(b[h].z * invj); pk.us[h*4+3] = f2bf(b[h].w * invj);
  }
  ((uint4*)(E + (size_t)(k + B_ROWS) * DIM))[lane] = pk.v;
  if (lane == 0) {
    pd[k] = dot * invi * invj;
    S[k] = 0.0f; S[k + B_ROWS] = 0.0f;
  }
}

// ---- symmetric Gram-GEMM + exp + row/col sums + last-block loss fold ----
__global__ __launch_bounds__(256) void ksimlse(const u16* __restrict__ E,
                                               float* __restrict__ S,
                                               const float* __restrict__ dist,
                                               const float* __restrict__ pd,
                                               float* __restrict__ out,
                                               unsigned int* __restrict__ cnt) {
  __shared__ u16 As[2][BM * BK];  // 2 x 8 KiB
  __shared__ u16 Bs[2][BN * BK];  // 2 x 8 KiB

  // triangular tile map: block t -> (I, J), J >= I, 64x64 tile grid
  const int t0 = blockIdx.x;
  int I = (int)(64.5f - sqrtf(4160.25f - 2.0f * (float)t0));
  if (I > 63) I = 63;
  int base = (129 * I - I * I) >> 1;
  if (base > t0) { --I; base = (129 * I - I * I) >> 1; }
  else {
    int nb = (129 * (I + 1) - (I + 1) * (I + 1)) >> 1;
    if (nb <= t0) { ++I; base = nb; }
  }
  const int J = I + (t0 - base);
  const int brow = I * BM, bcol = J * BN;
  const bool diag = (I == J);

  const int tid  = threadIdx.x;
  const int wid  = tid >> 6;
  const int lane = tid & 63;
  const int wr   = (wid >> 1) * 64;
  const int wc   = (wid & 1) * 64;
  const int g    = lane >> 4;
  const int lc   = lane & 15;

  const int    srow  = tid >> 2;
  const int    scol  = (tid & 3) * 8;
  const size_t aBase = (size_t)(brow + srow) * DIM + scol;
  const size_t bBase = (size_t)(bcol + srow) * DIM + scol;

  auto stage = [&](int b, int kk) {
#pragma unroll
    for (int it = 0; it < 2; ++it) {
      gload16(E + aBase + (size_t)it * 64 * DIM + kk,
              (char*)As + b * 8192 + it * 4096 + tid * 16);
      gload16(E + bBase + (size_t)it * 64 * DIM + kk,
              (char*)Bs + b * 8192 + it * 4096 + tid * 16);
    }
  };

  f32x4 acc[4][4] = {};

  stage(0, 0);
  __syncthreads();

#pragma unroll 1
  for (int t = 0; t < KSTEPS; ++t) {
    const int cur = t & 1;
    if (t + 1 < KSTEPS) stage(cur ^ 1, (t + 1) * BK);  // prefetch FIRST

    bf16x8 af[4], bfr[4];
#pragma unroll
    for (int mi = 0; mi < 4; ++mi)
      af[mi] = *(const bf16x8*)&As[cur][(wr + mi * 16 + lc) * BK + g * 8];
#pragma unroll
    for (int ni = 0; ni < 4; ++ni)
      bfr[ni] = *(const bf16x8*)&Bs[cur][(wc + ni * 16 + lc) * BK + g * 8];
#pragma unroll
    for (int mi = 0; mi < 4; ++mi)
#pragma unroll
      for (int ni = 0; ni < 4; ++ni)
        acc[mi][ni] = __builtin_amdgcn_mfma_f32_16x16x32_bf16(
            af[mi], bfr[ni], acc[mi][ni], 0, 0, 0);

    __syncthreads();  // one barrier/K-step: drains prefetch (vmcnt) + ds_reads
  }

  // epilogue: C/D layout col=lane&15, row=(lane>>4)*4+j  [m89/m91]
  float cs[4] = {0.f, 0.f, 0.f, 0.f};
#pragma unroll
  for (int mi = 0; mi < 4; ++mi) {
#pragma unroll
    for (int j = 0; j < 4; ++j) {
      const int Rg = brow + wr + mi * 16 + g * 4 + j;
      float rs = 0.0f;
#pragma unroll
      for (int ni = 0; ni < 4; ++ni) {
        const int Cg = bcol + wc + ni * 16 + lc;
        float e = __expf((acc[mi][ni][j] - 1.0f) * INV_TAU);
        if (diag && Rg == Cg) e = 0.0f;
        rs += e;
        cs[ni] += e;
      }
      rs += __shfl_xor(rs, 1);
      rs += __shfl_xor(rs, 2);
      rs += __shfl_xor(rs, 4);
      rs += __shfl_xor(rs, 8);
      if (lc == j) atomicAdd(&S[Rg], rs);
    }
  }
  if (!diag) {  // column sums -> S[c] (the mirrored half)
#pragma unroll
    for (int ni = 0; ni < 4; ++ni) {
      float c = cs[ni];
      c += __shfl_xor(c, 16);
      c += __shfl_xor(c, 32);
      if (g == 0) atomicAdd(&S[bcol + wc + ni * 16 + lc], c);
    }
  }

  // ---- last-block finisher (non-blocking: no spin, no grid sync) ----
  __shared__ int lastflag;
  __shared__ float sl[4], sn[4];
  __threadfence();  // release: this block's S atomics before counter RMW
  if (tid == 0)
    lastflag = (__hip_atomic_fetch_add(cnt, 1u, __ATOMIC_ACQ_REL,
                                       __HIP_MEMORY_SCOPE_AGENT) == NTILES - 1);
  __syncthreads();
  if (!lastflag) return;
  __threadfence();  // acquire: observe all other blocks' S atomics

  float ls = 0.0f, nv = 0.0f;
  for (int it = 0; it < B_ROWS / 256; ++it) {
    const int k = it * 256 + tid;
    if (dist[k] < POS_THRESH) {
      ls += logf(aload(&S[k])) + logf(aload(&S[k + B_ROWS])) + 2.0f * INV_TAU
          - 2.0f * pd[k] * INV_TAU;
      nv += 2.0f;
    }
  }
#pragma unroll
  for (int m = 1; m < 64; m <<= 1) {
    ls += __shfl_xor(ls, m); nv += __shfl_xor(nv, m);
  }
  if (lane == 0) { sl[wid] = ls; sn[wid] = nv; }
  __syncthreads();
  if (tid == 0) {
    const float L = sl[0] + sl[1] + sl[2] + sl[3];
    const float N = sn[0] + sn[1] + sn[2] + sn[3];
    out[0] = (N > 0.0f) ? (L / fmaxf(N, 1.0f)) : 0.0f;
  }
}

extern "C" void kernel_launch(void* const* d_in, const int* in_sizes, int n_in,
                              void* d_out, int out_size, void* d_ws, size_t ws_size,
                              hipStream_t stream) {
  const float* ei   = (const float*)d_in[0];
  const float* ej   = (const float*)d_in[1];
  const float* dist = (const float*)d_in[2];
  float* out = (float*)d_out;

  u16*   E  = (u16*)d_ws;
  float* S  = (float*)((char*)d_ws + (size_t)NROWS * DIM * sizeof(u16));
  float* pd = S + NROWS;
  unsigned int* cnt = (unsigned int*)(pd + B_ROWS);

  knorm2<<<B_ROWS / 4, 256, 0, stream>>>(ei, ej, E, S, pd, cnt);
  ksimlse<<<NTILES, 256, 0, stream>>>(E, S, dist, pd, out, cnt);
}

// Round 12
// 146.402 us; speedup vs baseline: 1.9380x; 1.9380x over previous
//
#include <hip/hip_runtime.h>
#include <cstdint>

// NT-Xent loss via symmetric bf16-MFMA Gram + fused exp/row-sum epilogue.
//  S[r] = sum_{c!=r} exp((dot(n_r,n_c)-1)/tau); lse[r] = log(S[r]) + 1/tau.
//  R12: R6 base + FENCE-FREE last-block finisher.
//    R11 lesson: per-block __threadfence / acq_rel RMW = agent-scope L2
//    writeback + L1/L2 INVALIDATE on every XCD -> E panels evicted ->
//    MfmaUtil 19%->6%, 3x regression. All S updates are device-scope
//    atomicAdds (coherence-point visible by default, m20), so the only
//    needed orderings are a local s_waitcnt vmcnt(0) before the counter
//    bump and relaxed agent-scope atomic loads of S in the last block.
// ws: [0,8MiB) E bf16 8192x512 | S[8192] f32 | pd[4096] f32 | cnt u32

#define B_ROWS 4096
#define NROWS  8192
#define DIM    512
#define NTILES 2080   // 64 diag + 2016 strict-upper 128x128 tiles

typedef unsigned short u16;

constexpr float INV_TAU    = 1.0f / 0.07f;
constexpr float POS_THRESH = 0.2f;
constexpr int BM = 128, BN = 128, BK = 32;
constexpr int KSTEPS = DIM / BK;   // 16

using f32x4  = __attribute__((ext_vector_type(4))) float;
using bf16x8 = __attribute__((ext_vector_type(8))) short;

static __device__ __forceinline__ u16 f2bf(float f) {
  union { float f; uint32_t u; } v; v.f = f;
  uint32_t r = v.u + 0x7fffu + ((v.u >> 16) & 1u);  // RNE
  return (u16)(r >> 16);
}

static __device__ __forceinline__ void gload16(const u16* g, void* l) {
  __builtin_amdgcn_global_load_lds(
      (const __attribute__((address_space(1))) void*)g,
      (__attribute__((address_space(3))) void*)l, 16, 0, 0);
}

static __device__ __forceinline__ float aload(const float* p) {
  return __hip_atomic_load(p, __ATOMIC_RELAXED, __HIP_MEMORY_SCOPE_AGENT);
}

// ---- knorm2: one wave per pair k. Normalize rows k and k+B to bf16,
//      fp32 pair cosine, zero S + tile counter. ----
__global__ __launch_bounds__(256) void knorm2(const float* __restrict__ ei,
                                              const float* __restrict__ ej,
                                              u16* __restrict__ E,
                                              float* __restrict__ S,
                                              float* __restrict__ pd,
                                              unsigned int* __restrict__ cnt) {
  if (blockIdx.x == 0 && threadIdx.x == 0) *cnt = 0u;
  const int k    = (blockIdx.x * 256 + threadIdx.x) >> 6;  // pair 0..4095
  const int lane = threadIdx.x & 63;
  const float4* pi = (const float4*)(ei + (size_t)k * DIM);
  const float4* pj = (const float4*)(ej + (size_t)k * DIM);
  float4 a[2] = { pi[lane * 2], pi[lane * 2 + 1] };
  float4 b[2] = { pj[lane * 2], pj[lane * 2 + 1] };
  float si = 0.f, sj = 0.f, dot = 0.f;
#pragma unroll
  for (int h = 0; h < 2; ++h) {
    si  += a[h].x*a[h].x + a[h].y*a[h].y + a[h].z*a[h].z + a[h].w*a[h].w;
    sj  += b[h].x*b[h].x + b[h].y*b[h].y + b[h].z*b[h].z + b[h].w*b[h].w;
    dot += a[h].x*b[h].x + a[h].y*b[h].y + a[h].z*b[h].z + a[h].w*b[h].w;
  }
#pragma unroll
  for (int m = 1; m < 64; m <<= 1) {
    si += __shfl_xor(si, m); sj += __shfl_xor(sj, m); dot += __shfl_xor(dot, m);
  }
  const float invi = 1.0f / sqrtf(si);
  const float invj = 1.0f / sqrtf(sj);
  union { u16 us[8]; uint4 v; } pk;
#pragma unroll
  for (int h = 0; h < 2; ++h) {
    pk.us[h*4+0] = f2bf(a[h].x * invi); pk.us[h*4+1] = f2bf(a[h].y * invi);
    pk.us[h*4+2] = f2bf(a[h].z * invi); pk.us[h*4+3] = f2bf(a[h].w * invi);
  }
  ((uint4*)(E + (size_t)k * DIM))[lane] = pk.v;
#pragma unroll
  for (int h = 0; h < 2; ++h) {
    pk.us[h*4+0] = f2bf(b[h].x * invj); pk.us[h*4+1] = f2bf(b[h].y * invj);
    pk.us[h*4+2] = f2bf(b[h].z * invj); pk.us[h*4+3] = f2bf(b[h].w * invj);
  }
  ((uint4*)(E + (size_t)(k + B_ROWS) * DIM))[lane] = pk.v;
  if (lane == 0) {
    pd[k] = dot * invi * invj;
    S[k] = 0.0f; S[k + B_ROWS] = 0.0f;
  }
}

// ---- symmetric Gram-GEMM + exp + row/col sums + fence-free finisher ----
__global__ __launch_bounds__(256) void ksimlse(const u16* __restrict__ E,
                                               float* __restrict__ S,
                                               const float* __restrict__ dist,
                                               const float* __restrict__ pd,
                                               float* __restrict__ out,
                                               unsigned int* __restrict__ cnt) {
  __shared__ u16 As[2][BM * BK];  // 2 x 8 KiB
  __shared__ u16 Bs[2][BN * BK];  // 2 x 8 KiB

  // triangular tile map: block t -> (I, J), J >= I, 64x64 tile grid
  const int t0 = blockIdx.x;
  int I = (int)(64.5f - sqrtf(4160.25f - 2.0f * (float)t0));
  if (I > 63) I = 63;
  int base = (129 * I - I * I) >> 1;
  if (base > t0) { --I; base = (129 * I - I * I) >> 1; }
  else {
    int nb = (129 * (I + 1) - (I + 1) * (I + 1)) >> 1;
    if (nb <= t0) { ++I; base = nb; }
  }
  const int J = I + (t0 - base);
  const int brow = I * BM, bcol = J * BN;
  const bool diag = (I == J);

  const int tid  = threadIdx.x;
  const int wid  = tid >> 6;
  const int lane = tid & 63;
  const int wr   = (wid >> 1) * 64;
  const int wc   = (wid & 1) * 64;
  const int g    = lane >> 4;
  const int lc   = lane & 15;

  const int    srow  = tid >> 2;
  const int    scol  = (tid & 3) * 8;
  const size_t aBase = (size_t)(brow + srow) * DIM + scol;
  const size_t bBase = (size_t)(bcol + srow) * DIM + scol;

  auto stage = [&](int b, int kk) {
#pragma unroll
    for (int it = 0; it < 2; ++it) {
      gload16(E + aBase + (size_t)it * 64 * DIM + kk,
              (char*)As + b * 8192 + it * 4096 + tid * 16);
      gload16(E + bBase + (size_t)it * 64 * DIM + kk,
              (char*)Bs + b * 8192 + it * 4096 + tid * 16);
    }
  };

  f32x4 acc[4][4] = {};

  stage(0, 0);
  __syncthreads();

#pragma unroll 1
  for (int t = 0; t < KSTEPS; ++t) {
    const int cur = t & 1;
    if (t + 1 < KSTEPS) stage(cur ^ 1, (t + 1) * BK);  // prefetch FIRST

    bf16x8 af[4], bfr[4];
#pragma unroll
    for (int mi = 0; mi < 4; ++mi)
      af[mi] = *(const bf16x8*)&As[cur][(wr + mi * 16 + lc) * BK + g * 8];
#pragma unroll
    for (int ni = 0; ni < 4; ++ni)
      bfr[ni] = *(const bf16x8*)&Bs[cur][(wc + ni * 16 + lc) * BK + g * 8];
#pragma unroll
    for (int mi = 0; mi < 4; ++mi)
#pragma unroll
      for (int ni = 0; ni < 4; ++ni)
        acc[mi][ni] = __builtin_amdgcn_mfma_f32_16x16x32_bf16(
            af[mi], bfr[ni], acc[mi][ni], 0, 0, 0);

    __syncthreads();  // one barrier/K-step: drains prefetch (vmcnt) + ds_reads
  }

  // epilogue: C/D layout col=lane&15, row=(lane>>4)*4+j  [m89/m91]
  float cs[4] = {0.f, 0.f, 0.f, 0.f};
#pragma unroll
  for (int mi = 0; mi < 4; ++mi) {
#pragma unroll
    for (int j = 0; j < 4; ++j) {
      const int Rg = brow + wr + mi * 16 + g * 4 + j;
      float rs = 0.0f;
#pragma unroll
      for (int ni = 0; ni < 4; ++ni) {
        const int Cg = bcol + wc + ni * 16 + lc;
        float e = __expf((acc[mi][ni][j] - 1.0f) * INV_TAU);
        if (diag && Rg == Cg) e = 0.0f;
        rs += e;
        cs[ni] += e;
      }
      rs += __shfl_xor(rs, 1);
      rs += __shfl_xor(rs, 2);
      rs += __shfl_xor(rs, 4);
      rs += __shfl_xor(rs, 8);
      if (lc == j) atomicAdd(&S[Rg], rs);
    }
  }
  if (!diag) {  // column sums -> S[c] (the mirrored half)
#pragma unroll
    for (int ni = 0; ni < 4; ++ni) {
      float c = cs[ni];
      c += __shfl_xor(c, 16);
      c += __shfl_xor(c, 32);
      if (g == 0) atomicAdd(&S[bcol + wc + ni * 16 + lc], c);
    }
  }

  // ---- fence-free last-block finisher ----
  // S writes are device-scope atomics (coherence-point visible, m20); only
  // need: (a) my atomics complete before my counter bump -> local vmcnt(0);
  // (b) last block reads S at coherence point -> relaxed agent atomic loads.
  // NO release writeback, NO acquire invalidate (R11's 3x poison).
  __shared__ int lastflag;
  __shared__ float sl[4], sn[4];
  asm volatile("s_waitcnt vmcnt(0)" ::: "memory");
  if (tid == 0)
    lastflag = (__hip_atomic_fetch_add(cnt, 1u, __ATOMIC_RELAXED,
                                       __HIP_MEMORY_SCOPE_AGENT) == NTILES - 1);
  __syncthreads();
  if (!lastflag) return;

  float ls = 0.0f, nv = 0.0f;
  for (int it = 0; it < B_ROWS / 256; ++it) {
    const int k = it * 256 + tid;
    if (dist[k] < POS_THRESH) {
      ls += logf(aload(&S[k])) + logf(aload(&S[k + B_ROWS])) + 2.0f * INV_TAU
          - 2.0f * pd[k] * INV_TAU;
      nv += 2.0f;
    }
  }
#pragma unroll
  for (int m = 1; m < 64; m <<= 1) {
    ls += __shfl_xor(ls, m); nv += __shfl_xor(nv, m);
  }
  if (lane == 0) { sl[wid] = ls; sn[wid] = nv; }
  __syncthreads();
  if (tid == 0) {
    const float L = sl[0] + sl[1] + sl[2] + sl[3];
    const float N = sn[0] + sn[1] + sn[2] + sn[3];
    out[0] = (N > 0.0f) ? (L / fmaxf(N, 1.0f)) : 0.0f;
  }
}

extern "C" void kernel_launch(void* const* d_in, const int* in_sizes, int n_in,
                              void* d_out, int out_size, void* d_ws, size_t ws_size,
                              hipStream_t stream) {
  const float* ei   = (const float*)d_in[0];
  const float* ej   = (const float*)d_in[1];
  const float* dist = (const float*)d_in[2];
  float* out = (float*)d_out;

  u16*   E  = (u16*)d_ws;
  float* S  = (float*)((char*)d_ws + (size_t)NROWS * DIM * sizeof(u16));
  float* pd = S + NROWS;
  unsigned int* cnt = (unsigned int*)(pd + B_ROWS);

  knorm2<<<B_ROWS / 4, 256, 0, stream>>>(ei, ej, E, S, pd, cnt);
  ksimlse<<<NTILES, 256, 0, stream>>>(E, S, dist, pd, out, cnt);
}